// Round 2
// baseline (298.229 us; speedup 1.0000x reference)
//
#include <hip/hip_runtime.h>
#include <hip/hip_bf16.h>
#include <math.h>

#define B_N 2048
#define MUL_N 128
#define C_N 128
#define NGA 7
#define NG 28           // 4 Gauss-Legendre x 7 azimuthal (exact for this band limit)
#define IN_DIM 2048
#define OUT_DIM 2048
#define KU 32
#define PI_D 3.14159265358979323846

// 1/( sqrt(128)*sqrt(128) * sqrt(4*C) ) = 1/(128*sqrt(512))
#define SCALE_OUT (1.0f / (128.0f * 22.62741699796952f))

// persistent device scratch (avoids relying on ws_size); fully rewritten every launch
__device__ float g_cout[(size_t)B_N * C_N * 36];
__device__ float g_Y[9 * NG];
__device__ float g_YW[9 * NG];

// ---------------------------------------------------------------------------
// Init: real orthonormal SH basis (L=2) on GL4 x uniform-7 grid + quadrature
// ---------------------------------------------------------------------------
__global__ void init_basis_kernel() {
    int g = threadIdx.x;
    if (g >= NG) return;
    int ib = g / NGA, ia = g - ib * NGA;
    const double xs[4] = {-0.8611363115940526, -0.3399810435848563,
                           0.3399810435848563,  0.8611363115940526};
    const double ws[4] = { 0.3478548451374538,  0.6521451548625461,
                           0.6521451548625461,  0.3478548451374538};
    double x = xs[ib], w = ws[ib];
    double s = sqrt(1.0 - x * x);
    double alpha = 2.0 * PI_D * (double)ia / (double)NGA;
    double P00 = sqrt(1.0 / (4.0 * PI_D));
    double P11 = -sqrt(3.0 / 2.0) * s * P00;
    double P22 = -sqrt(5.0 / 4.0) * s * P11;
    double P10 = sqrt(3.0) * x * P00;
    double P21 = sqrt(5.0) * x * P11;
    double P20 = sqrt(15.0 / 4.0) * (x * P10 - sqrt(1.0 / 3.0) * P00);
    double r2 = sqrt(2.0);
    double Y[9];
    Y[0] = P00;
    Y[1] = r2 * P11 * sin(alpha);
    Y[2] = P10;
    Y[3] = r2 * P11 * cos(alpha);
    Y[4] = r2 * P22 * sin(2.0 * alpha);
    Y[5] = r2 * P21 * sin(alpha);
    Y[6] = P20;
    Y[7] = r2 * P21 * cos(alpha);
    Y[8] = r2 * P22 * cos(2.0 * alpha);
    double qw = w * (2.0 * PI_D / (double)NGA);
    for (int k = 0; k < 9; ++k) {
        g_Y[k * NG + g]  = (float)Y[k];
        g_YW[k * NG + g] = (float)(Y[k] * qw);
    }
}

// ---------------------------------------------------------------------------
// Stage 1+2 fused: c1,c2 GEMM fragments in registers + spherical middle
// block = 256 threads, tile = 16 b-rows x 16 c-cols; thread (ty,tx) <-> (b,c)
// ---------------------------------------------------------------------------
template <int L>
__device__ inline void gemm_l(const float* __restrict__ x1, const float* __restrict__ x2,
                              const float* __restrict__ W1, const float* __restrict__ W2,
                              float* A1s, float* A2s, float* W1s, float* W2s,
                              int b0, int c0, int ty, int tx, int tid,
                              float (&acc1)[4][9], float (&acc2)[4][9]) {
    constexpr int D = 2 * L + 1;
    constexpr int BASE = MUL_N * L * L;   // 0 / 128 / 512
    constexpr int CH = KU * D;            // chunk elems per b-row
    constexpr int AP = CH + 1;            // padded pitch (conflict-free per-ty reads)
    for (int uc = 0; uc < MUL_N / KU; ++uc) {
        // stage x chunks (contiguous per row)
        for (int i = tid; i < 16 * CH; i += 256) {
            int r = i / CH;
            int j = i - r * CH;
            size_t gidx = (size_t)(b0 + r) * IN_DIM + BASE + uc * CH + j;
            A1s[r * AP + j] = x1[gidx];
            A2s[r * AP + j] = x2[gidx];
        }
        // stage W chunks: [ku][64] (64 = 16 c x 4 p, contiguous in global)
        for (int i = tid; i < KU * 64; i += 256) {
            int ku = i >> 6;
            int q  = i & 63;
            size_t gidx = (size_t)(L * MUL_N + uc * KU + ku) * 512 + (size_t)c0 * 4 + q;
            W1s[ku * 64 + q] = W1[gidx];
            W2s[ku * 64 + q] = W2[gidx];
        }
        __syncthreads();
        #pragma unroll 4
        for (int ku = 0; ku < KU; ++ku) {
            float4 wv1 = *reinterpret_cast<const float4*>(&W1s[ku * 64 + tx * 4]);
            float4 wv2 = *reinterpret_cast<const float4*>(&W2s[ku * 64 + tx * 4]);
            #pragma unroll
            for (int m = 0; m < D; ++m) {
                float a1 = A1s[ty * AP + ku * D + m];
                float a2 = A2s[ty * AP + ku * D + m];
                acc1[0][L * L + m] += a1 * wv1.x;
                acc1[1][L * L + m] += a1 * wv1.y;
                acc1[2][L * L + m] += a1 * wv1.z;
                acc1[3][L * L + m] += a1 * wv1.w;
                acc2[0][L * L + m] += a2 * wv2.x;
                acc2[1][L * L + m] += a2 * wv2.y;
                acc2[2][L * L + m] += a2 * wv2.z;
                acc2[3][L * L + m] += a2 * wv2.w;
            }
        }
        __syncthreads();
    }
}

__global__ __launch_bounds__(256) void coeff_mid_kernel(
        const float* __restrict__ x1, const float* __restrict__ x2,
        const float* __restrict__ W1, const float* __restrict__ W2) {
    __shared__ float A1s[16 * 161];
    __shared__ float A2s[16 * 161];
    __shared__ float W1s[KU * 64];
    __shared__ float W2s[KU * 64];
    __shared__ float Ys[9 * NG];
    __shared__ float YWs[9 * NG];

    int tid = threadIdx.x;
    int tx = tid & 15, ty = tid >> 4;
    int c0 = blockIdx.x * 16;
    int b0 = blockIdx.y * 16;

    for (int i = tid; i < 9 * NG; i += 256) {
        Ys[i]  = g_Y[i];
        YWs[i] = g_YW[i];
    }
    // first __syncthreads inside gemm_l<0> makes Ys/YWs visible before use

    float acc1[4][9], acc2[4][9];
    #pragma unroll
    for (int p = 0; p < 4; ++p)
        #pragma unroll
        for (int k = 0; k < 9; ++k) { acc1[p][k] = 0.f; acc2[p][k] = 0.f; }

    gemm_l<0>(x1, x2, W1, W2, A1s, A2s, W1s, W2s, b0, c0, ty, tx, tid, acc1, acc2);
    gemm_l<1>(x1, x2, W1, W2, A1s, A2s, W1s, W2s, b0, c0, ty, tx, tid, acc1, acc2);
    gemm_l<2>(x1, x2, W1, W2, A1s, A2s, W1s, W2s, b0, c0, ty, tx, tid, acc1, acc2);

    // middle: scalar product (p=0) + cross product (p=1..3) via exact quadrature
    float o[4][9];
    #pragma unroll
    for (int p = 0; p < 4; ++p)
        #pragma unroll
        for (int k = 0; k < 9; ++k) o[p][k] = 0.f;

    for (int g = 0; g < NG; ++g) {
        float y[9], wq[9];
        #pragma unroll
        for (int k = 0; k < 9; ++k) {
            y[k]  = Ys[k * NG + g];
            wq[k] = YWs[k * NG + g];
        }
        float s1[4], s2[4];
        #pragma unroll
        for (int p = 0; p < 4; ++p) {
            float t1 = 0.f, t2 = 0.f;
            #pragma unroll
            for (int k = 0; k < 9; ++k) {
                t1 += acc1[p][k] * y[k];
                t2 += acc2[p][k] * y[k];
            }
            s1[p] = t1;
            s2[p] = t2;
        }
        float sig[4];
        sig[0] = s1[0] * s2[0];
        sig[1] = s1[2] * s2[3] - s1[3] * s2[2];
        sig[2] = s1[3] * s2[1] - s1[1] * s2[3];
        sig[3] = s1[1] * s2[2] - s1[2] * s2[1];
        #pragma unroll
        for (int p = 0; p < 4; ++p)
            #pragma unroll
            for (int k = 0; k < 9; ++k) o[p][k] += sig[p] * wq[k];
    }

    // write 36 floats (9 x float4, 16B-aligned: pair stride = 144B)
    float of[36];
    #pragma unroll
    for (int p = 0; p < 4; ++p)
        #pragma unroll
        for (int k = 0; k < 9; ++k) of[p * 9 + k] = o[p][k];
    float* dst = g_cout + ((size_t)(b0 + ty) * C_N + (c0 + tx)) * 36;
    #pragma unroll
    for (int j = 0; j < 9; ++j) {
        float4 v = make_float4(of[4 * j], of[4 * j + 1], of[4 * j + 2], of[4 * j + 3]);
        *reinterpret_cast<float4*>(dst + 4 * j) = v;
    }
}

// ---------------------------------------------------------------------------
// Stage 3: out[b, off_l + u*d + m] = (1/(128*sqrt(512))) * sum_{c,p} c_out * Wout
// block = 256 threads, tile = 16 b-rows x all 128 u; K = 512 (c,p)
// ---------------------------------------------------------------------------
template <int L>
__device__ inline void out_gemm(const float* __restrict__ Wout,
                                float* __restrict__ out,
                                float* As, float* Ws, int r0, int tid) {
    constexpr int D = 2 * L + 1;
    constexpr int OFF = MUL_N * L * L;   // 0 / 128 / 512
    int tx = tid & 15, ty = tid >> 4;

    float acc[8][D];
    #pragma unroll
    for (int uu = 0; uu < 8; ++uu)
        #pragma unroll
        for (int m = 0; m < D; ++m) acc[uu][m] = 0.f;

    for (int kc = 0; kc < 512 / 64; ++kc) {
        int k0 = kc * 64;
        // stage Wout chunk [64][128]
        for (int i = tid; i < 64 * 128; i += 256) {
            int kk = i >> 7;
            int u  = i & 127;
            Ws[kk * 128 + u] = Wout[(size_t)L * 65536 + (size_t)(k0 + kk) * 128 + u];
        }
        // stage c_out chunk [16][64][D] (pitch 8 per kk, +1 per row for banks)
        for (int i = tid; i < 16 * 64 * D; i += 256) {
            int r   = i / (64 * D);
            int rem = i - r * (64 * D);
            int kk  = rem / D;
            int m   = rem - kk * D;
            As[r * 513 + kk * 8 + m] =
                g_cout[(size_t)(r0 + r) * 4608 + (size_t)(k0 + kk) * 9 + L * L + m];
        }
        __syncthreads();
        #pragma unroll 8
        for (int kk = 0; kk < 64; ++kk) {
            float am[D];
            #pragma unroll
            for (int m = 0; m < D; ++m) am[m] = As[ty * 513 + kk * 8 + m];
            #pragma unroll
            for (int uu = 0; uu < 8; ++uu) {
                float wv = Ws[kk * 128 + tx + 16 * uu];
                #pragma unroll
                for (int m = 0; m < D; ++m) acc[uu][m] += am[m] * wv;
            }
        }
        __syncthreads();
    }

    #pragma unroll
    for (int uu = 0; uu < 8; ++uu) {
        int u = tx + 16 * uu;
        #pragma unroll
        for (int m = 0; m < D; ++m) {
            out[(size_t)(r0 + ty) * OUT_DIM + OFF + u * D + m] = acc[uu][m] * SCALE_OUT;
        }
    }
}

__global__ __launch_bounds__(256) void out_kernel(const float* __restrict__ Wout,
                                                  float* __restrict__ out) {
    __shared__ float Ws[64 * 128];
    __shared__ float As[16 * 513];
    int r0 = blockIdx.x * 16;
    if (blockIdx.y == 0)      out_gemm<0>(Wout, out, As, Ws, r0, threadIdx.x);
    else if (blockIdx.y == 1) out_gemm<1>(Wout, out, As, Ws, r0, threadIdx.x);
    else                      out_gemm<2>(Wout, out, As, Ws, r0, threadIdx.x);
}

// ---------------------------------------------------------------------------
extern "C" void kernel_launch(void* const* d_in, const int* in_sizes, int n_in,
                              void* d_out, int out_size, void* d_ws, size_t ws_size,
                              hipStream_t stream) {
    const float* x1   = (const float*)d_in[0];
    const float* x2   = (const float*)d_in[1];
    const float* W1   = (const float*)d_in[2];
    const float* W2   = (const float*)d_in[3];
    const float* Wout = (const float*)d_in[4];
    float* out = (float*)d_out;

    // zero whole output (covers the l=3 zero tail); kernels overwrite cols [0,1152)
    hipMemsetAsync(d_out, 0, (size_t)out_size * sizeof(float), stream);

    init_basis_kernel<<<1, 64, 0, stream>>>();

    coeff_mid_kernel<<<dim3(C_N / 16, B_N / 16), 256, 0, stream>>>(x1, x2, W1, W2);

    out_kernel<<<dim3(B_N / 16, 3), 256, 0, stream>>>(Wout, out);
}

// Round 3
// 89.530 us; speedup vs baseline: 3.3310x; 3.3310x over previous
//
#include <hip/hip_runtime.h>
#include <math.h>

typedef short short8 __attribute__((ext_vector_type(8)));
typedef float f32x4 __attribute__((ext_vector_type(4)));

#define B_N 2048
#define NKM 9
#define CP 512          // C*4
#define KU 128          // MUL
#define NG 28
#define NGA 7
#define PI_D 3.14159265358979323846
#define INV_SQRT_MUL 0.08838834764831845f   // 1/sqrt(128)
#define INV_SQRT_4C  0.04419417382415922f   // 1/sqrt(512)

// persistent device scratch; fully rewritten every launch before any read
__device__ ushort g_xb1[NKM * B_N * KU];          // [km][b][u] bf16
__device__ ushort g_xb2[NKM * B_N * KU];
__device__ ushort g_W1bt[3 * CP * KU];            // [l][cp][u] bf16 (K=u contiguous), * 1/sqrt(128)
__device__ ushort g_W2bt[3 * CP * KU];
__device__ ushort g_Woutbt[3 * KU * CP];          // [l][u][cp] bf16 (K=cp contiguous), * 1/sqrt(512)
__device__ float  g_c1[(size_t)B_N * NKM * CP];   // [b][km][cp] fp32
__device__ float  g_c2[(size_t)B_N * NKM * CP];
__device__ ushort g_cb[(size_t)B_N * NKM * CP];   // c_out, bf16
__device__ float  g_Y[9 * NG];
__device__ float  g_YW[9 * NG];

__device__ __forceinline__ ushort f2b(float f) {
    uint u = __float_as_uint(f);
    uint r = (u + 0x7fffu + ((u >> 16) & 1u)) >> 16;   // RNE
    return (ushort)r;
}
__device__ __forceinline__ float b2f(ushort h) {
    return __uint_as_float(((uint)h) << 16);
}
__device__ __forceinline__ int l_of_km(int km) { return (km >= 4) ? 2 : (km >= 1 ? 1 : 0); }

// ---------------------------------------------------------------------------
// prep_small: W converts (768 blocks) + SH basis init (block 768)
// ---------------------------------------------------------------------------
__global__ void prep_small_kernel(const float* __restrict__ W1, const float* __restrict__ W2,
                                  const float* __restrict__ Wout) {
    int bid = blockIdx.x;
    if (bid == 768) {
        int g = threadIdx.x;
        if (g >= NG) return;
        int ib = g / NGA, ia = g - ib * NGA;
        const double xs[4] = {-0.8611363115940526, -0.3399810435848563,
                               0.3399810435848563,  0.8611363115940526};
        const double ws[4] = { 0.3478548451374538,  0.6521451548625461,
                               0.6521451548625461,  0.3478548451374538};
        double x = xs[ib], w = ws[ib];
        double s = sqrt(1.0 - x * x);
        double alpha = 2.0 * PI_D * (double)ia / (double)NGA;
        double P00 = sqrt(1.0 / (4.0 * PI_D));
        double P11 = -sqrt(3.0 / 2.0) * s * P00;
        double P22 = -sqrt(5.0 / 4.0) * s * P11;
        double P10 = sqrt(3.0) * x * P00;
        double P21 = sqrt(5.0) * x * P11;
        double P20 = sqrt(15.0 / 4.0) * (x * P10 - sqrt(1.0 / 3.0) * P00);
        double r2 = sqrt(2.0);
        double Y[9];
        Y[0] = P00;
        Y[1] = r2 * P11 * sin(alpha);
        Y[2] = P10;
        Y[3] = r2 * P11 * cos(alpha);
        Y[4] = r2 * P22 * sin(2.0 * alpha);
        Y[5] = r2 * P21 * sin(alpha);
        Y[6] = P20;
        Y[7] = r2 * P21 * cos(alpha);
        Y[8] = r2 * P22 * cos(2.0 * alpha);
        double qw = w * (2.0 * PI_D / (double)NGA);
        for (int k = 0; k < 9; ++k) {
            g_Y[k * NG + g]  = (float)Y[k];
            g_YW[k * NG + g] = (float)(Y[k] * qw);
        }
        return;
    }
    int idx = bid * 256 + threadIdx.x;       // < 3*512*128 = 196608
    int l = idx >> 16;
    int r = idx & 65535;
    {   // W1bt/W2bt [l][cp][u]  <-  W[l][u][cp] * 1/sqrt(128)
        int cp = r >> 7, u = r & 127;
        float w1 = W1[(size_t)l * 65536 + (size_t)u * 512 + cp] * INV_SQRT_MUL;
        float w2 = W2[(size_t)l * 65536 + (size_t)u * 512 + cp] * INV_SQRT_MUL;
        g_W1bt[idx] = f2b(w1);
        g_W2bt[idx] = f2b(w2);
    }
    {   // Woutbt [l][u][cp]  <-  Wout[l][cp][u] * 1/sqrt(512)
        int u = r >> 9, cp = r & 511;
        float w = Wout[(size_t)l * 65536 + (size_t)cp * 128 + u] * INV_SQRT_4C;
        g_Woutbt[idx] = f2b(w);
    }
}

// ---------------------------------------------------------------------------
// prep_x: x [B,2048] fp32 -> xb [km][B][u] bf16 (m-major, K-contiguous)
// ---------------------------------------------------------------------------
__global__ void prep_x_kernel(const float* __restrict__ x1, const float* __restrict__ x2) {
    int idx = blockIdx.x * 256 + threadIdx.x;   // < 9*2048*128
    int km = idx >> 18;
    int b  = (idx >> 7) & 2047;
    int u  = idx & 127;
    int l = l_of_km(km);
    int mi = km - l * l;
    int col = l * l * 128 + u * (2 * l + 1) + mi;
    g_xb1[idx] = f2b(x1[(size_t)b * 2048 + col]);
    g_xb2[idx] = f2b(x2[(size_t)b * 2048 + col]);
}

// ---------------------------------------------------------------------------
// gemm_c: c[b][km][cp] = sum_u xb[km][b][u] * Wbt[l][cp][u]   (fp32 out)
// grid (32 m-tiles, 8 n-tiles, 18 = field*9+km), 64x64 tile, K=128 resident
// ---------------------------------------------------------------------------
__global__ __launch_bounds__(256) void gemm_c_kernel() {
    __shared__ ushort As[64 * 128];
    __shared__ ushort Bs[64 * 128];
    int tid = threadIdx.x;
    int z = blockIdx.z;
    int field = (z >= NKM);
    int km = field ? z - NKM : z;
    int l = l_of_km(km);
    int b0 = blockIdx.x * 64, n0 = blockIdx.y * 64;
    const ushort* xa = (field ? g_xb2 : g_xb1) + (size_t)km * (B_N * KU);
    const ushort* wb = (field ? g_W2bt : g_W1bt) + (size_t)l * 65536;
    float* cdst = field ? g_c2 : g_c1;

    #pragma unroll
    for (int it = 0; it < 4; ++it) {
        int i = it * 256 + tid;            // 16B chunk id, 0..1023
        int row = i >> 4, kg = i & 15;
        int dst = row * 128 + ((kg ^ (row & 7)) << 3);
        *(short8*)&As[dst] = *(const short8*)&xa[(size_t)(b0 + row) * KU + (kg << 3)];
        *(short8*)&Bs[dst] = *(const short8*)&wb[(size_t)(n0 + row) * KU + (kg << 3)];
    }
    __syncthreads();

    int lane = tid & 63, wid = tid >> 6, wr = wid >> 1, wc = wid & 1;
    f32x4 acc[2][2];
    #pragma unroll
    for (int i = 0; i < 2; ++i)
        #pragma unroll
        for (int j = 0; j < 2; ++j) acc[i][j] = (f32x4){0.f, 0.f, 0.f, 0.f};

    #pragma unroll
    for (int ks = 0; ks < 4; ++ks) {
        int kg = ks * 4 + (lane >> 4);
        short8 a[2], b[2];
        #pragma unroll
        for (int i = 0; i < 2; ++i) {
            int row = wr * 32 + i * 16 + (lane & 15);
            a[i] = *(const short8*)&As[row * 128 + ((kg ^ (row & 7)) << 3)];
        }
        #pragma unroll
        for (int j = 0; j < 2; ++j) {
            int row = wc * 32 + j * 16 + (lane & 15);
            b[j] = *(const short8*)&Bs[row * 128 + ((kg ^ (row & 7)) << 3)];
        }
        #pragma unroll
        for (int i = 0; i < 2; ++i)
            #pragma unroll
            for (int j = 0; j < 2; ++j)
                acc[i][j] = __builtin_amdgcn_mfma_f32_16x16x32_bf16(a[i], b[j], acc[i][j], 0, 0, 0);
    }

    #pragma unroll
    for (int i = 0; i < 2; ++i)
        #pragma unroll
        for (int j = 0; j < 2; ++j)
            #pragma unroll
            for (int r = 0; r < 4; ++r) {
                int row = b0 + wr * 32 + i * 16 + ((lane >> 4) << 2) + r;
                int col = n0 + wc * 32 + j * 16 + (lane & 15);
                cdst[((size_t)row * NKM + km) * CP + col] = acc[i][j][r];
            }
}

// ---------------------------------------------------------------------------
// middle: per (b,c) scalar/cross product on the 28-pt grid (verified math)
// ---------------------------------------------------------------------------
__global__ __launch_bounds__(256) void middle_kernel() {
    __shared__ float Ys[9 * NG], YWs[9 * NG];
    int tid = threadIdx.x;
    for (int i = tid; i < 9 * NG; i += 256) { Ys[i] = g_Y[i]; YWs[i] = g_YW[i]; }
    __syncthreads();

    int idx = blockIdx.x * 256 + tid;
    int b = idx >> 7, c = idx & 127;

    float c1[4][9], c2[4][9];
    #pragma unroll
    for (int k = 0; k < 9; ++k) {
        float4 v1 = *(const float4*)&g_c1[((size_t)b * NKM + k) * CP + c * 4];
        float4 v2 = *(const float4*)&g_c2[((size_t)b * NKM + k) * CP + c * 4];
        c1[0][k] = v1.x; c1[1][k] = v1.y; c1[2][k] = v1.z; c1[3][k] = v1.w;
        c2[0][k] = v2.x; c2[1][k] = v2.y; c2[2][k] = v2.z; c2[3][k] = v2.w;
    }

    float o[4][9];
    #pragma unroll
    for (int p = 0; p < 4; ++p)
        #pragma unroll
        for (int k = 0; k < 9; ++k) o[p][k] = 0.f;

    for (int g = 0; g < NG; ++g) {
        float y[9], wq[9];
        #pragma unroll
        for (int k = 0; k < 9; ++k) { y[k] = Ys[k * NG + g]; wq[k] = YWs[k * NG + g]; }
        float s1[4], s2[4];
        #pragma unroll
        for (int p = 0; p < 4; ++p) {
            float t1 = 0.f, t2 = 0.f;
            #pragma unroll
            for (int k = 0; k < 9; ++k) { t1 += c1[p][k] * y[k]; t2 += c2[p][k] * y[k]; }
            s1[p] = t1; s2[p] = t2;
        }
        float sig[4];
        sig[0] = s1[0] * s2[0];
        sig[1] = s1[2] * s2[3] - s1[3] * s2[2];
        sig[2] = s1[3] * s2[1] - s1[1] * s2[3];
        sig[3] = s1[1] * s2[2] - s1[2] * s2[1];
        #pragma unroll
        for (int p = 0; p < 4; ++p)
            #pragma unroll
            for (int k = 0; k < 9; ++k) o[p][k] += sig[p] * wq[k];
    }

    #pragma unroll
    for (int k = 0; k < 9; ++k) {
        ushort4 v;
        v.x = f2b(o[0][k]); v.y = f2b(o[1][k]); v.z = f2b(o[2][k]); v.w = f2b(o[3][k]);
        *(ushort4*)&g_cb[((size_t)b * NKM + k) * CP + c * 4] = v;
    }
}

// ---------------------------------------------------------------------------
// out_gemm: out[b][OFF_l + u*d + mi] = sum_cp c_out[b][km][cp] * Woutb[l][cp][u]
// grid (32 m-tiles, 2 n-tiles, 9 km), 64x64 tile, K=512 in 4 chunks
// ---------------------------------------------------------------------------
__global__ __launch_bounds__(256) void out_gemm_kernel(float* __restrict__ out) {
    __shared__ ushort As[64 * 128];
    __shared__ ushort Bs[64 * 128];
    int tid = threadIdx.x;
    int km = blockIdx.z;
    int l = l_of_km(km);
    int mi = km - l * l, d = 2 * l + 1, OFF = 128 * l * l;
    int b0 = blockIdx.x * 64, u0 = blockIdx.y * 64;

    int lane = tid & 63, wid = tid >> 6, wr = wid >> 1, wc = wid & 1;
    f32x4 acc[2][2];
    #pragma unroll
    for (int i = 0; i < 2; ++i)
        #pragma unroll
        for (int j = 0; j < 2; ++j) acc[i][j] = (f32x4){0.f, 0.f, 0.f, 0.f};

    for (int kc = 0; kc < 4; ++kc) {
        #pragma unroll
        for (int it = 0; it < 4; ++it) {
            int i = it * 256 + tid;
            int row = i >> 4, kg = i & 15;
            int dst = row * 128 + ((kg ^ (row & 7)) << 3);
            *(short8*)&As[dst] = *(const short8*)&g_cb[(size_t)(b0 + row) * (NKM * CP)
                                                       + (size_t)km * CP + kc * 128 + (kg << 3)];
            *(short8*)&Bs[dst] = *(const short8*)&g_Woutbt[(size_t)l * 65536
                                                       + (size_t)(u0 + row) * CP + kc * 128 + (kg << 3)];
        }
        __syncthreads();
        #pragma unroll
        for (int ks = 0; ks < 4; ++ks) {
            int kg = ks * 4 + (lane >> 4);
            short8 a[2], b[2];
            #pragma unroll
            for (int i = 0; i < 2; ++i) {
                int row = wr * 32 + i * 16 + (lane & 15);
                a[i] = *(const short8*)&As[row * 128 + ((kg ^ (row & 7)) << 3)];
            }
            #pragma unroll
            for (int j = 0; j < 2; ++j) {
                int row = wc * 32 + j * 16 + (lane & 15);
                b[j] = *(const short8*)&Bs[row * 128 + ((kg ^ (row & 7)) << 3)];
            }
            #pragma unroll
            for (int i = 0; i < 2; ++i)
                #pragma unroll
                for (int j = 0; j < 2; ++j)
                    acc[i][j] = __builtin_amdgcn_mfma_f32_16x16x32_bf16(a[i], b[j], acc[i][j], 0, 0, 0);
        }
        __syncthreads();
    }

    #pragma unroll
    for (int i = 0; i < 2; ++i)
        #pragma unroll
        for (int j = 0; j < 2; ++j)
            #pragma unroll
            for (int r = 0; r < 4; ++r) {
                int row = b0 + wr * 32 + i * 16 + ((lane >> 4) << 2) + r;
                int u   = u0 + wc * 32 + j * 16 + (lane & 15);
                out[(size_t)row * 2048 + OFF + u * d + mi] = acc[i][j][r];
            }
}

// ---------------------------------------------------------------------------
extern "C" void kernel_launch(void* const* d_in, const int* in_sizes, int n_in,
                              void* d_out, int out_size, void* d_ws, size_t ws_size,
                              hipStream_t stream) {
    const float* x1   = (const float*)d_in[0];
    const float* x2   = (const float*)d_in[1];
    const float* W1   = (const float*)d_in[2];
    const float* W2   = (const float*)d_in[3];
    const float* Wout = (const float*)d_in[4];
    float* out = (float*)d_out;

    hipMemsetAsync(d_out, 0, (size_t)out_size * sizeof(float), stream);  // l=3 zero tail

    prep_small_kernel<<<769, 256, 0, stream>>>(W1, W2, Wout);
    prep_x_kernel<<<9216, 256, 0, stream>>>(x1, x2);

    gemm_c_kernel<<<dim3(B_N / 64, CP / 64, 18), 256, 0, stream>>>();
    middle_kernel<<<(B_N * 128) / 256, 256, 0, stream>>>();
    out_gemm_kernel<<<dim3(B_N / 64, 128 / 64, NKM), 256, 0, stream>>>(out);
}